// Round 16
// baseline (94.121 us; speedup 1.0000x reference)
//
#include <hip/hip_runtime.h>
#include <hip/hip_fp16.h>
#include <stdint.h>

// Local-window (5x5) KDE histogram entropy, 256 bins, bandwidth 0.1.
// R16 = R15 x3 DIAGNOSTIC (entropy kernel only, via grid.y; rep 0 -> d_out,
// reps 1,2 -> d_ws at 4MB/8MB, past the 3.84MB mass table). Since R7 the
// ~21-23us kernel is invisible under the harness's 40us fills; R13-R15
// op-cuts each returned ~10% vs modeled 25-30% -> model is 3-4x off. This
// buys ground truth: VGPR/spill (pressure?), VALUBusy (issue- vs
// stall-bound?) for the CURRENT merged structure. Algorithm unchanged:
// register-resident O(25^2) prefix-merge, telescoping T2 = sum_b M log2 M,
// H = ln2*(log2 S - T2/S); bare v_log_f32; 4-op pair body (b0<<4 stored;
// s = med3(A_i - b0sh_j, 0, 63); t = lo32(pk64_j >> s); Ppk = pk_add(Ppk,t)).

#define W   96
#define H   96
#define WP  100          // padded side
#define IMG (W*H)        // 9216
#define IMGP (WP*WP)     // 10000
#define TPB 256

#if __has_builtin(__builtin_amdgcn_logf)
__device__ __forceinline__ float rawlog2(float v) {
    return __builtin_amdgcn_logf(v);
}
#else
__device__ __forceinline__ float rawlog2(float v) {
    float r;
    asm("v_log_f32 %0, %1\n\ts_nop 1" : "=v"(r) : "v"(v));
    return r;
}
#endif

__global__ __launch_bounds__(TPB) void mass_kernel(
    const float* __restrict__ x, uint4* __restrict__ wm, int total2)
{
    const int pid = blockIdx.x * TPB + threadIdx.x;
    if (pid >= total2) return;
    const int x2  = pid % WP;
    const int y2  = (pid / WP) % WP;
    const int img = pid / IMGP;

    uint4 e;
    if (x2 >= 2 && x2 < WP - 2 && y2 >= 2 && y2 < WP - 2) {
        const float v  = x[img * IMG + (y2 - 2) * W + (x2 - 2)];
        const int   b0 = (int)v;                    // v in [0,255) -> [0,254]
        const float f  = v - (float)b0;
        const float E  = __expf(-10.f * f);
        const float E2 = __expf(10.f * f - 10.f);
        const float r0 = __builtin_amdgcn_rcpf(1.f + E);
        const float r1 = __builtin_amdgcn_rcpf(1.f + E2);
        const float k0 = E  * r0 * r0;              // mass at bin b0
        const float k1 = E2 * r1 * r1;              // mass at bin b0+1
        const __half2 hk = __floats2half2_rn(k0, k1);
        const float2  kc = __half22float2(hk);      // fp16-rounded, used in S,T
        e.x = __builtin_bit_cast(uint32_t, hk);
        e.y = (uint32_t)(b0 << 4);                  // pre-shifted for pair body
        e.z = __builtin_bit_cast(uint32_t, kc.x);
        e.w = __builtin_bit_cast(uint32_t, kc.y);
    } else {
        e.x = 0u;                                   // zero mass
        e.y = (uint32_t)(1 << 20);                  // clamps s to an end -> t=0
        e.z = 0u;
        e.w = 0u;
    }
    wm[pid] = e;
}

__global__ __launch_bounds__(TPB) void entropy_kde_kernel(
    const uint4* __restrict__ wm, float* __restrict__ out,
    float* __restrict__ ws_out)
{
    const int px   = blockIdx.x * TPB + threadIdx.x;  // grid.x exact: 864*256
    const int rep  = blockIdx.y;                      // 0,1,2 identical work
    const int xcol = px % W;
    const int y    = (px / W) % H;
    const int img  = px / IMG;
    const uint4* __restrict__ wb = wm + img * IMGP + y * WP + xcol;

    uint64_t pk64[25];
    int      bsh [25];
    float S0 = 0.f, S1 = 0.f;
    float T0 = 0.f, T1 = 0.f, T2a = 0.f, T3 = 0.f;

    #pragma unroll
    for (int i = 0; i < 25; ++i) {
        const int dy = i / 5, dx = i % 5;
        const uint4 m = wb[dy * WP + dx];            // base + imm offset
        const int   A  = (int)m.y + 32;              // b0i<<4 + 32
        const float k0 = __builtin_bit_cast(float, m.z);
        const float k1 = __builtin_bit_cast(float, m.w);
        if (i & 1) S1 += k0 + k1; else S0 += k0 + k1;

        uint32_t Ppk = 0u;
        #pragma unroll
        for (int j = 0; j < i; ++j) {
            int s = A - bsh[j];                      // 16d + 32
            s = s < 0 ? 0 : (s > 63 ? 63 : s);       // v_med3_i32
            const uint32_t t = (uint32_t)(pk64[j] >> s);
            const __half2 sum = __hadd2(__builtin_bit_cast(__half2, Ppk),
                                        __builtin_bit_cast(__half2, t));
            Ppk = __builtin_bit_cast(uint32_t, sum);
        }
        const float2 P  = __half22float2(__builtin_bit_cast(__half2, Ppk));
        const float z0 = P.x + k0, z1 = P.y + k1;
        const float t4 = z0  * rawlog2(z0  + 1e-10f) - P.x * rawlog2(P.x + 1e-10f)
                       + z1  * rawlog2(z1  + 1e-10f) - P.y * rawlog2(P.y + 1e-10f);
        if      ((i & 3) == 0) T0  += t4;
        else if ((i & 3) == 1) T1  += t4;
        else if ((i & 3) == 2) T2a += t4;
        else                   T3  += t4;

        bsh[i]  = (int)m.y;
        pk64[i] = ((uint64_t)m.x) << 32;
    }

    const float S  = (S0 + S1) + 1e-10f;
    const float T  = (T0 + T1) + (T2a + T3);
    const float Hv = 0.69314718056f * (rawlog2(S) - T / S);
    if (rep == 0) out[px] = Hv;
    else          ws_out[rep * (1 << 20) + px] = Hv;   // 4MB/8MB byte offsets
}

extern "C" void kernel_launch(void* const* d_in, const int* in_sizes, int n_in,
                              void* d_out, int out_size, void* d_ws, size_t ws_size,
                              hipStream_t stream)
{
    const float* x = (const float*)d_in[0];
    float* out = (float*)d_out;
    uint4* wm  = (uint4*)d_ws;                       // 24*10000*16B = 3.84 MB
    float* wsf = (float*)d_ws;                       // rep sinks at 4MB/8MB
    const int total  = in_sizes[0];                  // 8*3*96*96 = 221184
    const int total2 = (total / IMG) * IMGP;         // 240000 padded entries
    mass_kernel<<<(total2 + TPB - 1) / TPB, TPB, 0, stream>>>(x, wm, total2);
    dim3 grid(total / TPB, 3, 1);                    // (864, 3): rep in y
    entropy_kde_kernel<<<grid, TPB, 0, stream>>>(wm, out, wsf);
}

// Round 17
// 70.257 us; speedup vs baseline: 1.3397x; 1.3397x over previous
//
#include <hip/hip_runtime.h>
#include <hip/hip_fp16.h>
#include <stdint.h>

// Local-window (5x5) KDE histogram entropy, 256 bins, bandwidth 0.1.
// sigma'((x-b)/0.1) ~ exp(-10|x-b|): only bins b0=floor(v), b0+1 carry mass
// (truncation err ~2e-3 vs 6.28e-2 threshold; validated R5-R16).
// Register-resident O(25^2) prefix-merge, telescoping T2 = sum_b M log2 M;
// H = ln2*(log2 S - T2/S); bare v_log_f32.
//
// R17: R16 diagnostic: VGPR 96, no spills, VALUBusy 66% @ 10 waves/SIMD,
// per-rep 14.6us vs 21us single-shot. Diagnosis: i-major pair loop = 24-deep
// serial v_pk_add_f16 chains (4-6cy dep each); 34% idle even at high
// occupancy, worse at the real 3.375 waves/SIMD. Fixes:
//  (1) j-major pair loop: inner iterations update DIFFERENT P[i] -> no
//      back-to-back deps; pk64_j + c_j=32-bsh_j hoisted to outer loop.
//      Same per-P_i accumulation order (j ascending) -> bit-identical.
//  (2) ws entry shrunk to uint2 (pk, b0<<4): k0/k1 re-derived by 2
//      v_cvt_f32_f16 in the T-loop; halves tap traffic, frees ~40 VGPRs.
// Pair body (4 ops): s_raw = bsh_i + c_j; s = med3(s_raw,0,63);
//   t = lo32(pk64_j >> s); P_i = v_pk_add_f16(P_i, t).
//   d=0 -> pk; d=1 -> pk>>16; d=-1 -> pk<<16; clamp ends -> 0.
//   Sentinel b0sh = 1<<20 forces clamp -> never deposits, never matches.

#define W   96
#define H   96
#define WP  100          // padded side
#define IMG (W*H)        // 9216
#define IMGP (WP*WP)     // 10000
#define TPB 256

#if __has_builtin(__builtin_amdgcn_logf)
__device__ __forceinline__ float rawlog2(float v) {
    return __builtin_amdgcn_logf(v);
}
#else
__device__ __forceinline__ float rawlog2(float v) {
    float r;
    asm("v_log_f32 %0, %1\n\ts_nop 1" : "=v"(r) : "v"(v));
    return r;
}
#endif

__global__ __launch_bounds__(TPB) void mass_kernel(
    const float* __restrict__ x, uint2* __restrict__ wm, int total2)
{
    const int pid = blockIdx.x * TPB + threadIdx.x;
    if (pid >= total2) return;
    const int x2  = pid % WP;
    const int y2  = (pid / WP) % WP;
    const int img = pid / IMGP;

    uint2 e;
    if (x2 >= 2 && x2 < WP - 2 && y2 >= 2 && y2 < WP - 2) {
        const float v  = x[img * IMG + (y2 - 2) * W + (x2 - 2)];
        const int   b0 = (int)v;                    // v in [0,255) -> [0,254]
        const float f  = v - (float)b0;
        const float E  = __expf(-10.f * f);
        const float E2 = __expf(10.f * f - 10.f);
        const float r0 = __builtin_amdgcn_rcpf(1.f + E);
        const float r1 = __builtin_amdgcn_rcpf(1.f + E2);
        const float k0 = E  * r0 * r0;              // mass at bin b0
        const float k1 = E2 * r1 * r1;              // mass at bin b0+1
        const __half2 hk = __floats2half2_rn(k0, k1);
        e.x = __builtin_bit_cast(uint32_t, hk);
        e.y = (uint32_t)(b0 << 4);                  // pre-shifted for pair body
    } else {
        e.x = 0u;                                   // zero mass
        e.y = (uint32_t)(1 << 20);                  // clamps s to an end -> t=0
    }
    wm[pid] = e;
}

__global__ __launch_bounds__(TPB) void entropy_kde_kernel(
    const uint2* __restrict__ wm, float* __restrict__ out)
{
    const int px   = blockIdx.x * TPB + threadIdx.x;  // grid exact: 864*256
    const int xcol = px % W;
    const int y    = (px / W) % H;
    const int img  = px / IMG;
    // padded base: tap(dy,dx) = wb[dy*WP+dx], dy,dx in 0..4 (imm offsets)
    const uint2* __restrict__ wb = wm + img * IMGP + y * WP + xcol;

    uint32_t pk [25];
    int      bsh[25];
    uint32_t P  [25];

    // ---- taps: 25 independent dwordx2 loads at base+imm ----
    #pragma unroll
    for (int i = 0; i < 25; ++i) {
        const uint2 m = wb[(i / 5) * WP + (i % 5)];
        pk[i]  = m.x;
        bsh[i] = (int)m.y;
        P[i]   = 0u;
    }

    // ---- pair loop, j-major: inner iterations hit DIFFERENT P[i] ----
    #pragma unroll
    for (int j = 0; j < 24; ++j) {
        const uint64_t pkj = ((uint64_t)pk[j]) << 32;  // hoisted per j
        const int      cj  = 32 - bsh[j];              // hoisted per j
        #pragma unroll
        for (int i = j + 1; i < 25; ++i) {
            int s = bsh[i] + cj;                       // 16d + 32
            s = s < 0 ? 0 : (s > 63 ? 63 : s);         // v_med3_i32
            const uint32_t t = (uint32_t)(pkj >> s);
            const __half2 sum = __hadd2(__builtin_bit_cast(__half2, P[i]),
                                        __builtin_bit_cast(__half2, t));
            P[i] = __builtin_bit_cast(uint32_t, sum);
        }
    }

    // ---- telescoping entropy terms ----
    float S0 = 0.f, S1 = 0.f;
    float T0 = 0.f, T1 = 0.f, T2a = 0.f, T3 = 0.f;
    #pragma unroll
    for (int i = 0; i < 25; ++i) {
        const float2 kc = __half22float2(__builtin_bit_cast(__half2, pk[i]));
        const float2 Pv = __half22float2(__builtin_bit_cast(__half2, P[i]));
        if (i & 1) S1 += kc.x + kc.y; else S0 += kc.x + kc.y;
        const float z0 = Pv.x + kc.x, z1 = Pv.y + kc.y;
        // h(z) = z*log2(z+eps); h(0)=0; k=0 (sentinel/OOB) -> z==P -> cancels
        const float t4 = z0 * rawlog2(z0 + 1e-10f) - Pv.x * rawlog2(Pv.x + 1e-10f)
                       + z1 * rawlog2(z1 + 1e-10f) - Pv.y * rawlog2(Pv.y + 1e-10f);
        if      ((i & 3) == 0) T0  += t4;
        else if ((i & 3) == 1) T1  += t4;
        else if ((i & 3) == 2) T2a += t4;
        else                   T3  += t4;
    }

    const float S = (S0 + S1) + 1e-10f;
    const float T = (T0 + T1) + (T2a + T3);
    // H = ln S - (sum m ln m)/S = ln2 * (log2 S - T/S)
    out[px] = 0.69314718056f * (rawlog2(S) - T / S);
}

extern "C" void kernel_launch(void* const* d_in, const int* in_sizes, int n_in,
                              void* d_out, int out_size, void* d_ws, size_t ws_size,
                              hipStream_t stream)
{
    const float* x = (const float*)d_in[0];
    float* out = (float*)d_out;
    uint2* wm  = (uint2*)d_ws;                       // 24*10000*8B = 1.92 MB
    const int total  = in_sizes[0];                  // 8*3*96*96 = 221184
    const int total2 = (total / IMG) * IMGP;         // 240000 padded entries
    mass_kernel<<<(total2 + TPB - 1) / TPB, TPB, 0, stream>>>(x, wm, total2);
    entropy_kde_kernel<<<total / TPB, TPB, 0, stream>>>(wm, out);
}

// Round 18
// 69.400 us; speedup vs baseline: 1.3562x; 1.0123x over previous
//
#include <hip/hip_runtime.h>
#include <hip/hip_fp16.h>
#include <stdint.h>

// Local-window (5x5) KDE histogram entropy, 256 bins, bandwidth 0.1.
// sigma'((x-b)/0.1) ~ exp(-10|x-b|): only bins b0=floor(v), b0+1 carry mass
// (truncation err ~2e-3 vs 6.28e-2 threshold; validated R5-R17).
// Register-resident O(25^2) prefix-merge, telescoping T2 = sum_b M log2 M;
// H = ln2*(log2 S - T2/S); bare v_log_f32; 4-op pair body.
//
// R18: occupancy attack, de-confounded. R16 measured the same code at 10
// waves/SIMD running 30% faster per unit than single-shot (14.6 vs 21us);
// grid gives only 3.375 waves/SIMD. R10/R11's role-split test was poisoned
// by pre-two-pass redundant mass recompute (+19% chip VALU); post-two-pass
// the only redundancy is 17 extra 8B L2 tap loads. Split, template-static:
//   role A: outputs i in [0,17)  (136 pairs, taps 0..16)
//   role B: outputs i in [17,25) (164 pairs, taps 0..24)
// Same per-output j-ascending order -> bit-identical (absmax 0.015625).
// Waves 3456 -> 6912 (6.75/SIMD); per-wave issue ~halved; 1KB LDS combine.

#define W   96
#define H   96
#define WP  100          // padded side
#define IMG (W*H)        // 9216
#define IMGP (WP*WP)     // 10000
#define TPB 256

#if __has_builtin(__builtin_amdgcn_logf)
__device__ __forceinline__ float rawlog2(float v) {
    return __builtin_amdgcn_logf(v);
}
#else
__device__ __forceinline__ float rawlog2(float v) {
    float r;
    asm("v_log_f32 %0, %1\n\ts_nop 1" : "=v"(r) : "v"(v));
    return r;
}
#endif

__global__ __launch_bounds__(TPB) void mass_kernel(
    const float* __restrict__ x, uint2* __restrict__ wm, int total2)
{
    const int pid = blockIdx.x * TPB + threadIdx.x;
    if (pid >= total2) return;
    const int x2  = pid % WP;
    const int y2  = (pid / WP) % WP;
    const int img = pid / IMGP;

    uint2 e;
    if (x2 >= 2 && x2 < WP - 2 && y2 >= 2 && y2 < WP - 2) {
        const float v  = x[img * IMG + (y2 - 2) * W + (x2 - 2)];
        const int   b0 = (int)v;                    // v in [0,255) -> [0,254]
        const float f  = v - (float)b0;
        const float E  = __expf(-10.f * f);
        const float E2 = __expf(10.f * f - 10.f);
        const float r0 = __builtin_amdgcn_rcpf(1.f + E);
        const float r1 = __builtin_amdgcn_rcpf(1.f + E2);
        const float k0 = E  * r0 * r0;              // mass at bin b0
        const float k1 = E2 * r1 * r1;              // mass at bin b0+1
        const __half2 hk = __floats2half2_rn(k0, k1);
        e.x = __builtin_bit_cast(uint32_t, hk);
        e.y = (uint32_t)(b0 << 4);                  // pre-shifted for pair body
    } else {
        e.x = 0u;                                   // zero mass
        e.y = (uint32_t)(1 << 20);                  // clamps s to an end -> t=0
    }
    wm[pid] = e;
}

// Outputs i in [I0, I1): loads taps 0..I1-1, accumulates P for its outputs
// (j ascending per output -> same order as the unsplit kernel), then its
// share of S and T.  All register-array indices compile-time after unroll.
template<int I0, int I1>
__device__ __forceinline__ void role_compute(const uint2* __restrict__ wb,
                                             float& Sout, float& Tout)
{
    uint32_t pk[I1]; int bsh[I1];
    #pragma unroll
    for (int i = 0; i < I1; ++i) {
        const uint2 m = wb[(i / 5) * WP + (i % 5)];
        pk[i]  = m.x;
        bsh[i] = (int)m.y;
    }

    uint32_t P[I1 - I0];
    #pragma unroll
    for (int t = 0; t < I1 - I0; ++t) P[t] = 0u;

    // pair loop, j-major over my outputs only
    #pragma unroll
    for (int j = 0; j < I1 - 1; ++j) {
        const uint64_t pkj = ((uint64_t)pk[j]) << 32;
        const int      cj  = 32 - bsh[j];
        #pragma unroll
        for (int i = (j + 1 > I0 ? j + 1 : I0); i < I1; ++i) {
            int s = bsh[i] + cj;                    // 16d + 32
            s = s < 0 ? 0 : (s > 63 ? 63 : s);      // v_med3_i32
            const uint32_t t = (uint32_t)(pkj >> s);
            const __half2 sum = __hadd2(__builtin_bit_cast(__half2, P[i - I0]),
                                        __builtin_bit_cast(__half2, t));
            P[i - I0] = __builtin_bit_cast(uint32_t, sum);
        }
    }

    float S0 = 0.f, S1 = 0.f;
    float T0 = 0.f, T1 = 0.f;
    #pragma unroll
    for (int i = I0; i < I1; ++i) {
        const float2 kc = __half22float2(__builtin_bit_cast(__half2, pk[i]));
        const float2 Pv = __half22float2(__builtin_bit_cast(__half2, P[i - I0]));
        if (i & 1) S1 += kc.x + kc.y; else S0 += kc.x + kc.y;
        const float z0 = Pv.x + kc.x, z1 = Pv.y + kc.y;
        // h(z) = z*log2(z+eps); h(0)=0; k=0 (sentinel/OOB) -> z==P -> cancels
        const float t4 = z0 * rawlog2(z0 + 1e-10f) - Pv.x * rawlog2(Pv.x + 1e-10f)
                       + z1 * rawlog2(z1 + 1e-10f) - Pv.y * rawlog2(Pv.y + 1e-10f);
        if (i & 1) T1 += t4; else T0 += t4;
    }
    Sout = S0 + S1;
    Tout = T0 + T1;
}

__global__ __launch_bounds__(TPB) void entropy_kde_kernel(
    const uint2* __restrict__ wm, float* __restrict__ out, int total)
{
    __shared__ float sS[128], sT[128];
    const int tid  = threadIdx.x;
    const int wv   = tid >> 6;          // wave 0..3
    const int g    = wv >> 1;           // pixel group 0/1 (64 px each)
    const int r    = wv & 1;            // role: 0 = A (i<17), 1 = B (i>=17)
    const int wl   = tid & 63;
    const int slot = g * 64 + wl;
    const int px   = blockIdx.x * 128 + slot;

    const int xcol = px % W;
    const int y    = (px / W) % H;
    const int img  = px / IMG;
    const uint2* __restrict__ wb = wm + img * IMGP + y * WP + xcol;

    float S, T;
    if (r == 0) role_compute<0, 17>(wb, S, T);
    else        role_compute<17, 25>(wb, S, T);

    if (r == 1) { sS[slot] = S; sT[slot] = T; }
    __syncthreads();
    if (r == 0) {
        S += sS[slot];
        T += sT[slot];
        const float Sp = S + 1e-10f;
        if (px < total) out[px] = 0.69314718056f * (rawlog2(Sp) - T / Sp);
    }
}

extern "C" void kernel_launch(void* const* d_in, const int* in_sizes, int n_in,
                              void* d_out, int out_size, void* d_ws, size_t ws_size,
                              hipStream_t stream)
{
    const float* x = (const float*)d_in[0];
    float* out = (float*)d_out;
    uint2* wm  = (uint2*)d_ws;                       // 24*10000*8B = 1.92 MB
    const int total  = in_sizes[0];                  // 8*3*96*96 = 221184
    const int total2 = (total / IMG) * IMGP;         // 240000 padded entries
    mass_kernel<<<(total2 + TPB - 1) / TPB, TPB, 0, stream>>>(x, wm, total2);
    entropy_kde_kernel<<<total / 128, TPB, 0, stream>>>(wm, out, total);
}